// Round 7
// baseline (200.872 us; speedup 1.0000x reference)
//
#include <hip/hip_runtime.h>

typedef __attribute__((ext_vector_type(4))) float f32x4;
typedef __attribute__((ext_vector_type(8))) short s16x8;
typedef __attribute__((ext_vector_type(4))) short s16x4;
typedef __bf16 bf16x4 __attribute__((ext_vector_type(4)));

#define B_   96
#define NQ   35
#define LP   180
#define H_   768
#define D_   128
#define NEGF (-1e30f)

#define NROWS 37920
#define QROWS 3360
#define PROWS 17280

__device__ __forceinline__ unsigned short f2bf(float f) {
    return __builtin_bit_cast(unsigned short, (__bf16)f);
}

__device__ __forceinline__ s16x4 cvt_bf4(f32x4 v) {
    return __builtin_bit_cast(s16x4, __builtin_convertvector(v, bf16x4));
}

__device__ __forceinline__ s16x8 pack_bf16(f32x4 v0, f32x4 v1) {
    bf16x4 h0 = __builtin_convertvector(v0, bf16x4);
    bf16x4 h1 = __builtin_convertvector(v1, bf16x4);
    s16x4 a = __builtin_bit_cast(s16x4, h0), b = __builtin_bit_cast(s16x4, h1);
    return __builtin_shufflevector(a, b, 0, 1, 2, 3, 4, 5, 6, 7);
}

// async global->LDS, 16 B per lane; lds dest must be wave-uniform (HW adds lane*16)
__device__ __forceinline__ void glds16(const void* g, void* l) {
    __builtin_amdgcn_global_load_lds(
        (const __attribute__((address_space(1))) unsigned int*)g,
        (__attribute__((address_space(3))) unsigned int*)l,
        16, 0, 0);
}

// 16B global load via inline asm (SGPR base + 32-bit VGPR offset): the compiler inserts
// NO waitcnt for asm defs, so these participate in the hand-counted vmcnt schedule.
__device__ __forceinline__ s16x8 ldg16(const unsigned short* sbase, unsigned int voff) {
    s16x8 r;
    asm volatile("global_load_dwordx4 %0, %1, %2"
                 : "=v"(r) : "v"(voff), "s"(sbase));
    return r;
}

#define WAITV(N) do {                                                 \
    asm volatile("s_waitcnt vmcnt(" #N ")" ::: "memory");             \
    __builtin_amdgcn_sched_barrier(0);                                \
} while (0)

#define BAR() do {                                                    \
    __builtin_amdgcn_sched_barrier(0);                                \
    __builtin_amdgcn_s_barrier();                                     \
} while (0)

// per-lane A-row source: unified global row -> matrix select + inverse-swizzled chunk.
// q/p/n boundaries (3360, 20640) are 4-aligned so a 4-row glds group may straddle them
// safely (each lane picks its own base). Rows >= NROWS (block 592 phantom tail) clamp to
// the last row: staged garbage, discarded by the epilogue guard.
__device__ __forceinline__ const float* rowsrc(const float* qh, const float* ph,
                                               const float* nh, int r, int lane) {
    int rc = r < (NROWS - 1) ? r : (NROWS - 1);
    const float* p;
    if (rc < QROWS)              p = qh + (size_t)rc * H_;
    else if (rc < QROWS + PROWS) p = ph + (size_t)(rc - QROWS) * H_;
    else                         p = nh + (size_t)(rc - QROWS - PROWS) * H_;
    return p + (((lane & 15) ^ (2 * (rc & 7))) << 2);
}

// ---------------- prep: wt_build (blocks 0-47) + ssq zero (48-191) + mask detect (192) ----
__global__ __launch_bounds__(256) void prep_k(
    const float* __restrict__ W, unsigned short* __restrict__ wthi,
    const unsigned int* __restrict__ pmask_w, unsigned int* __restrict__ ctrl,
    float* __restrict__ ssq) {
    __shared__ unsigned int rr[256];
    int b = blockIdx.x, t = threadIdx.x;
    if (b < 48) {
        int tid = b * 256 + t;
        int nt = tid / (24 * 64);
        int r = tid - nt * 24 * 64;
        int ks = r / 64, lane = r - ks * 64;
        int m = lane & 15, quad = lane >> 4;
        unsigned short* o = wthi + (size_t)tid * 8;
#pragma unroll
        for (int j = 0; j < 8; j++) {
            int k = ks * 32 + quad * 8 + j;
            o[j] = f2bf(W[(size_t)k * D_ + nt * 16 + m]);
        }
    } else if (b < 192) {
        ssq[(b - 48) * 256 + t] = 0.f;       // 144*256 = 36864 exactly
    } else {
        unsigned int f1 = 0, f3 = 0, f4 = 0;
        for (int w = t; w < 4320; w += 256) {
            unsigned int v = pmask_w[w];
            f1 |= v & 0x0000ff00u;                 // byte %4==1 -> 1-byte layout
            f3 |= v & 0xff000000u;                 // byte %4==3 -> float32
            if (w & 1) f4 |= v & 0x000000ffu;      // byte %8==4 -> int32
        }
        rr[t] = f1; __syncthreads();
        for (int s2 = 128; s2; s2 >>= 1) { if (t < s2) rr[t] |= rr[t + s2]; __syncthreads(); }
        if (!t) ctrl[0] = rr[0];
        __syncthreads();
        rr[t] = f3; __syncthreads();
        for (int s2 = 128; s2; s2 >>= 1) { if (t < s2) rr[t] |= rr[t + s2]; __syncthreads(); }
        if (!t) ctrl[1] = rr[0];
        __syncthreads();
        rr[t] = f4; __syncthreads();
        for (int s2 = 128; s2; s2 >>= 1) { if (t < s2) rr[t] |= rr[t + s2]; __syncthreads(); }
        if (!t) ctrl[2] = rr[0];
    }
}

// ---------------- proj v9: 64-row tiles -- HALVE the B-fragment traffic ----------------
// R5 verdict: four sync structures (v3/v6/v7/v8: drain-barriers / lgkm-only / counted
// ring-1 / counted group-ring-4) are EXACTLY tied at 47-51 us. Sync, prefetch depth and
// barrier count are irrelevant. What fits all six datapoints is a TRAFFIC model: dur ~
// (A 116 + B 192KB*blocks + writes 20) MB / ~8 TB/s effective (v5 doubled B -> 64 us;
// v4 doubled effective A -> 68 us; traffic-constant variants tied). v9 pulls the one
// untouched lever: 64-row x 128-col blocks (593) halve B to 114 MB -> 250 MB total.
// Structure: 3-slot glds LDS ring (48 KB, 3 blocks/CU); stage issued AFTER the barrier
// (slot s+2 = slot s-1 is only rewritten once all waves passed ACOMP(s-1)); B lead-2
// register rotation (sets sa/sb/sc). Steady ledger (G=4 glds, B=4 loads per step),
// issue order G0 B0 G1 B1 then per step [WAITV(8) -> BAR -> issue G(s+2),B(s+2) ->
// ACOMP(s)]: WAITV(8) retires exactly {G(s),B(s)}, keeps {G(s+1),B(s+1)} in flight.
// Arithmetic per output element identical to v3-v8 (same fragments, k-order, epilogue).
// (R6 resubmission: container-level infra failure, kernel re-audited for hang safety --
// uniform barriers, no-op-safe vmcnt waits, aligned boundaries, guarded tail.)
#define STAGE64(S) do {                                                                   \
    float* dst = &lds[((S) % 3) * 4096 + wave * 1024];                                    \
    glds16(gq0 + (S) * 64, dst);                                                          \
    glds16(gq1 + (S) * 64, dst + 256);                                                    \
    glds16(gq2 + (S) * 64, dst + 512);                                                    \
    glds16(gq3 + (S) * 64, dst + 768);                                                    \
} while (0)

#define LDB(p0, p1, p2, p3, S1) do {                                                      \
    unsigned int k0 = (unsigned int)((S1) * 2048u);                                       \
    p0 = ldg16(wthi, ob0 + k0);                                                           \
    p1 = ldg16(wthi, ob1 + k0);                                                           \
    p2 = ldg16(wthi, ob0 + k0 + 1024u);                                                   \
    p3 = ldg16(wthi, ob1 + k0 + 1024u);                                                   \
} while (0)

#define ACOMP64(S, B0, B1, B2, B3) do {                                                   \
    const float* bb = &lds[((S) % 3) * 4096];                                             \
    f32x4 l, h; s16x8 a0, a1, a2, a3;                                                     \
    l = *(const f32x4*)(bb + rbm0 + cA0); h = *(const f32x4*)(bb + rbm0 + cA0 + 4);       \
    a0 = pack_bf16(l, h);                                                                 \
    l = *(const f32x4*)(bb + rbm1 + cA0); h = *(const f32x4*)(bb + rbm1 + cA0 + 4);       \
    a1 = pack_bf16(l, h);                                                                 \
    l = *(const f32x4*)(bb + rbm2 + cA0); h = *(const f32x4*)(bb + rbm2 + cA0 + 4);       \
    a2 = pack_bf16(l, h);                                                                 \
    l = *(const f32x4*)(bb + rbm3 + cA0); h = *(const f32x4*)(bb + rbm3 + cA0 + 4);       \
    a3 = pack_bf16(l, h);                                                                 \
    acc[0][0] = __builtin_amdgcn_mfma_f32_16x16x32_bf16(a0, B0, acc[0][0], 0, 0, 0);      \
    acc[0][1] = __builtin_amdgcn_mfma_f32_16x16x32_bf16(a0, B1, acc[0][1], 0, 0, 0);      \
    acc[1][0] = __builtin_amdgcn_mfma_f32_16x16x32_bf16(a1, B0, acc[1][0], 0, 0, 0);      \
    acc[1][1] = __builtin_amdgcn_mfma_f32_16x16x32_bf16(a1, B1, acc[1][1], 0, 0, 0);      \
    acc[2][0] = __builtin_amdgcn_mfma_f32_16x16x32_bf16(a2, B0, acc[2][0], 0, 0, 0);      \
    acc[2][1] = __builtin_amdgcn_mfma_f32_16x16x32_bf16(a2, B1, acc[2][1], 0, 0, 0);      \
    acc[3][0] = __builtin_amdgcn_mfma_f32_16x16x32_bf16(a3, B0, acc[3][0], 0, 0, 0);      \
    acc[3][1] = __builtin_amdgcn_mfma_f32_16x16x32_bf16(a3, B1, acc[3][1], 0, 0, 0);      \
    l = *(const f32x4*)(bb + rbm0 + cA1); h = *(const f32x4*)(bb + rbm0 + cA1 + 4);       \
    a0 = pack_bf16(l, h);                                                                 \
    l = *(const f32x4*)(bb + rbm1 + cA1); h = *(const f32x4*)(bb + rbm1 + cA1 + 4);       \
    a1 = pack_bf16(l, h);                                                                 \
    l = *(const f32x4*)(bb + rbm2 + cA1); h = *(const f32x4*)(bb + rbm2 + cA1 + 4);       \
    a2 = pack_bf16(l, h);                                                                 \
    l = *(const f32x4*)(bb + rbm3 + cA1); h = *(const f32x4*)(bb + rbm3 + cA1 + 4);       \
    a3 = pack_bf16(l, h);                                                                 \
    acc[0][0] = __builtin_amdgcn_mfma_f32_16x16x32_bf16(a0, B2, acc[0][0], 0, 0, 0);      \
    acc[0][1] = __builtin_amdgcn_mfma_f32_16x16x32_bf16(a0, B3, acc[0][1], 0, 0, 0);      \
    acc[1][0] = __builtin_amdgcn_mfma_f32_16x16x32_bf16(a1, B2, acc[1][0], 0, 0, 0);      \
    acc[1][1] = __builtin_amdgcn_mfma_f32_16x16x32_bf16(a1, B3, acc[1][1], 0, 0, 0);      \
    acc[2][0] = __builtin_amdgcn_mfma_f32_16x16x32_bf16(a2, B2, acc[2][0], 0, 0, 0);      \
    acc[2][1] = __builtin_amdgcn_mfma_f32_16x16x32_bf16(a2, B3, acc[2][1], 0, 0, 0);      \
    acc[3][0] = __builtin_amdgcn_mfma_f32_16x16x32_bf16(a3, B2, acc[3][0], 0, 0, 0);      \
    acc[3][1] = __builtin_amdgcn_mfma_f32_16x16x32_bf16(a3, B3, acc[3][1], 0, 0, 0);      \
} while (0)

__global__ __launch_bounds__(256, 3) void proj_k(
    const float* __restrict__ qh, const float* __restrict__ ph, const float* __restrict__ nh,
    const unsigned short* __restrict__ wthi, const float* __restrict__ bias,
    float* __restrict__ x, float* __restrict__ ssq,
    const void* __restrict__ pm, const void* __restrict__ nm,
    const unsigned int* __restrict__ ctrl, unsigned char* __restrict__ maskc) {
    __shared__ float lds[12288];                     // 3-ring x 64 rows x 64 f32 = 48 KB
    int b = blockIdx.x;
    if (b >= 593) {                                  // ---- mask canon: 135 blocks exact ----
        int i = (b - 593) * 256 + threadIdx.x;       // < 34560
        const void* src = (i < B_ * LP) ? pm : nm;
        int j = (i < B_ * LP) ? i : i - B_ * LP;
        unsigned int c1 = ctrl[0], c3 = ctrl[1], c4 = ctrl[2];
        bool bit;
        if (c1 > 0)       bit = ((const unsigned char*)src)[j] != 0;
        else if (c3 > 0)  bit = ((const float*)src)[j] != 0.0f;
        else if (c4 > 0)  bit = ((const int*)src)[j] != 0;
        else              bit = ((const long long*)src)[j] != 0;
        maskc[i] = bit ? 1 : 0;
        return;
    }
    int t = threadIdx.x;
    int wave = t >> 6, lane = t & 63;
    int row0 = b * 64;                               // unified global row space
    int m = lane & 15, quad = lane >> 4;

    // staging: wave w covers rows [row0+16w, row0+16w+16) via 4 glds (4 rows each)
    int rbase = row0 + wave * 16 + (lane >> 4);
    const float* gq0 = rowsrc(qh, ph, nh, rbase,      lane);
    const float* gq1 = rowsrc(qh, ph, nh, rbase + 4,  lane);
    const float* gq2 = rowsrc(qh, ph, nh, rbase + 8,  lane);
    const float* gq3 = rowsrc(qh, ph, nh, rbase + 12, lane);

    // B fragment byte offsets into wthi (advance 2048 B per k-step)
    int nt0 = wave * 2, nt1 = wave * 2 + 1;
    unsigned int ob0 = (unsigned int)(((nt0 * 24) * 64 + lane) * 16);
    unsigned int ob1 = (unsigned int)(((nt1 * 24) * 64 + lane) * 16);

    // read-side swizzled LDS addresses (float units); row = mt*16 + m
    int swz = 2 * (m & 7);
    int rbm0 = m * 64, rbm1 = rbm0 + 1024, rbm2 = rbm0 + 2048, rbm3 = rbm0 + 3072;
    int cA0 = ((quad * 2) ^ swz) * 4;
    int cA1 = ((8 + quad * 2) ^ swz) * 4;

    f32x4 acc[4][2];
#pragma unroll
    for (int mt = 0; mt < 4; mt++)
#pragma unroll
        for (int ntl = 0; ntl < 2; ntl++) acc[mt][ntl] = (f32x4){0.f, 0.f, 0.f, 0.f};

    s16x8 sa0, sa1, sa2, sa3;                        // B steps 0,3,6,9
    s16x8 sb0, sb1, sb2, sb3;                        // B steps 1,4,7,10
    s16x8 sc0, sc1, sc2, sc3;                        // B steps 2,5,8,11

    // prologue (ledger order): G0 B0 G1 B1 = 16 outstanding
    STAGE64(0); LDB(sa0, sa1, sa2, sa3, 0);
    STAGE64(1); LDB(sb0, sb1, sb2, sb3, 1);

    // per step: WAITV(8) retires {G(s),B(s)}; BAR; issue {G(s+2),B(s+2)}; compute s
    WAITV(8); BAR(); STAGE64(2);  LDB(sc0, sc1, sc2, sc3, 2);  ACOMP64(0,  sa0, sa1, sa2, sa3);
    WAITV(8); BAR(); STAGE64(3);  LDB(sa0, sa1, sa2, sa3, 3);  ACOMP64(1,  sb0, sb1, sb2, sb3);
    WAITV(8); BAR(); STAGE64(4);  LDB(sb0, sb1, sb2, sb3, 4);  ACOMP64(2,  sc0, sc1, sc2, sc3);
    WAITV(8); BAR(); STAGE64(5);  LDB(sc0, sc1, sc2, sc3, 5);  ACOMP64(3,  sa0, sa1, sa2, sa3);
    WAITV(8); BAR(); STAGE64(6);  LDB(sa0, sa1, sa2, sa3, 6);  ACOMP64(4,  sb0, sb1, sb2, sb3);
    WAITV(8); BAR(); STAGE64(7);  LDB(sb0, sb1, sb2, sb3, 7);  ACOMP64(5,  sc0, sc1, sc2, sc3);
    WAITV(8); BAR(); STAGE64(8);  LDB(sc0, sc1, sc2, sc3, 8);  ACOMP64(6,  sa0, sa1, sa2, sa3);
    WAITV(8); BAR(); STAGE64(9);  LDB(sa0, sa1, sa2, sa3, 9);  ACOMP64(7,  sb0, sb1, sb2, sb3);
    WAITV(8); BAR(); STAGE64(10); LDB(sb0, sb1, sb2, sb3, 10); ACOMP64(8,  sc0, sc1, sc2, sc3);
    WAITV(8); BAR(); STAGE64(11); LDB(sc0, sc1, sc2, sc3, 11); ACOMP64(9,  sa0, sa1, sa2, sa3);
    WAITV(8); BAR();                                           ACOMP64(10, sb0, sb1, sb2, sb3);
    WAITV(0); BAR();                                           ACOMP64(11, sc0, sc1, sc2, sc3);

    // epilogue: x write + fused ssq (wave owns cols [wave*32, wave*32+32), 64 rows)
#pragma unroll
    for (int mt = 0; mt < 4; mt++) {
        int base = row0 + mt * 16;
        if (base < NROWS) {                          // guard block 592's phantom tail
            int bk0, bk1, b1start;
            if (base < QROWS)              { bk0 = base / 35;  bk1 = (base + 15) / 35;
                                             b1start = bk1 * 35; }
            else if (base < QROWS + PROWS) { int r0e = base - QROWS;
                                             bk0 = 96 + r0e / 180;  bk1 = 96 + (r0e + 15) / 180;
                                             b1start = QROWS + (bk1 - 96) * 180; }
            else                           { int r0e = base - QROWS - PROWS;
                                             bk0 = 192 + r0e / 180; bk1 = 192 + (r0e + 15) / 180;
                                             b1start = QROWS + PROWS + (bk1 - 192) * 180; }
#pragma unroll
            for (int ntl = 0; ntl < 2; ntl++) {
                int col = (wave * 2 + ntl) * 16 + m;
                float bv = bias[col];
                f32x4 s4 = acc[mt][ntl];
                float slo = 0.f, shi = 0.f;
#pragma unroll
                for (int r = 0; r < 4; r++) {
                    int grow = base + quad * 4 + r;
                    float v = s4[r] + bv;
                    x[(size_t)grow * D_ + col] = v;
                    float v2 = v * v;
                    if (bk1 > bk0 && grow >= b1start) shi += v2; else slo += v2;
                }
                slo += __shfl_xor(slo, 16); slo += __shfl_xor(slo, 32);
                if (quad == 0) atomicAdd(ssq + (size_t)bk0 * D_ + col, slo);
                if (bk1 > bk0) {
                    shi += __shfl_xor(shi, 16); shi += __shfl_xor(shi, 32);
                    if (quad == 0) atomicAdd(ssq + (size_t)bk1 * D_ + col, shi);
                }
            }
        }
    }
}

// ---------------- scale + bf16 + scatter: one thread per 16B frag chunk -----------------
__global__ __launch_bounds__(256) void scatter_k(
    const float* __restrict__ x, const float* __restrict__ ssq,
    const unsigned char* __restrict__ maskc,
    unsigned short* __restrict__ qfrag, unsigned short* __restrict__ pfrag) {
    int c = blockIdx.x * 256 + threadIdx.x;          // 651264 total = 2544*256
    int lane = c & 63, ks = (c >> 6) & 3;
    int quad = lane >> 4, mm = lane & 15;
    int d0 = ks * 32 + quad * 8;
    if (c < 61440) {
        int g = c >> 8;                              // qp*5 + mt
        int mt = g % 5, qp = g / 5;
        int prow = mt * 16 + mm;
        s16x8 outv = (s16x8){0, 0, 0, 0, 0, 0, 0, 0};
        if (prow < 70) {
            int hi = prow >= 35;
            int bq = qp * 2 + hi;
            int l = prow - hi * 35;
            size_t row = (size_t)bq * 35 + l;
            const f32x4* px = (const f32x4*)(x + row * D_ + d0);
            f32x4 v0 = px[0], v1 = px[1];
            const f32x4* pq = (const f32x4*)(ssq + (size_t)bq * D_ + d0);
            f32x4 q0 = pq[0], q1 = pq[1];
            f32x4 r0, r1;
#pragma unroll
            for (int j = 0; j < 4; j++) {
                r0[j] = rsqrtf(fmaxf(q0[j], 1e-24f));
                r1[j] = rsqrtf(fmaxf(q1[j], 1e-24f));
            }
            outv = pack_bf16(v0 * r0, v1 * r1);
        }
        *(s16x8*)(qfrag + (size_t)c * 8) = outv;
    } else {
        int c2 = c - 61440;
        int g = c2 >> 8;                             // pbk*12 + nt
        int nt = g % 12, pbk = g / 12;
        int l = nt * 16 + mm;
        int lsrc = (l < LP && maskc[pbk * LP + l]) ? l : 0;
        size_t row = QROWS + (size_t)pbk * LP + lsrc;
        const f32x4* px = (const f32x4*)(x + row * D_ + d0);
        f32x4 v0 = px[0], v1 = px[1];
        const f32x4* pq = (const f32x4*)(ssq + (size_t)(96 + pbk) * D_ + d0);
        f32x4 q0 = pq[0], q1 = pq[1];
        f32x4 r0, r1;
#pragma unroll
        for (int j = 0; j < 4; j++) {
            r0[j] = rsqrtf(fmaxf(q0[j], 1e-24f));
            r1[j] = rsqrtf(fmaxf(q1[j], 1e-24f));
        }
        *(s16x8*)(pfrag + (size_t)c2 * 8) = pack_bf16(v0 * r0, v1 * r1);
    }
}

// ---------------- late interaction: p-block staged via glds, XCD-pinned, mask-free ------
__global__ __launch_bounds__(256, 3) void interact_k(
    const unsigned short* __restrict__ qfrag, const unsigned short* __restrict__ pfrag,
    float* __restrict__ out) {
    __shared__ unsigned short plds[24576];           // 48 KB, shared by all 4 waves
    int wave = threadIdx.x >> 6, lane = threadIdx.x & 63;
    int b = blockIdx.x;                              // 2304 blocks
    int xcd = b & 7, i = b >> 3;                     // i in [0,288)
    int c = xcd * 24 + (i % 24);                     // [0,192)
    int qg = i / 24;                                 // [0,12)
    int side = c / 96, pb = c - side * 96;
    int qp = qg * 4 + wave;
    int m = lane & 15, quad = lane >> 4;

    const unsigned short* pbase = pfrag + (size_t)c * 24576;
    const unsigned short* qbase = qfrag + (size_t)qp * 10240;

#pragma unroll
    for (int ntl = 0; ntl < 3; ntl++) {
        int nt = wave * 3 + ntl;
#pragma unroll
        for (int ks = 0; ks < 4; ks++)
            glds16(pbase + ((size_t)(nt * 4 + ks) * 64 + lane) * 8,
                   &plds[(size_t)(nt * 4 + ks) * 512]);
    }

    s16x8 a[5][4];
#pragma unroll
    for (int mt = 0; mt < 5; mt++)
#pragma unroll
        for (int ks = 0; ks < 4; ks++)
            a[mt][ks] = *(const s16x8*)(qbase + ((size_t)(mt * 4 + ks) * 64 + lane) * 8);

    __syncthreads();                                 // drain staging

    const f32x4 zero4 = (f32x4){0.f, 0.f, 0.f, 0.f};
    float rmax[5][4];
#pragma unroll
    for (int mt = 0; mt < 5; mt++)
#pragma unroll
        for (int rr = 0; rr < 4; rr++) rmax[mt][rr] = NEGF;

    for (int nt = 0; nt < 12; nt++) {
        s16x8 bfr[4];
#pragma unroll
        for (int ks = 0; ks < 4; ks++)
            bfr[ks] = *(const s16x8*)&plds[((size_t)(nt * 4 + ks) * 64 + lane) * 8];
#pragma unroll
        for (int mt = 0; mt < 5; mt++) {
            f32x4 acc = __builtin_amdgcn_mfma_f32_16x16x32_bf16(a[mt][0], bfr[0], zero4, 0, 0, 0);
            acc = __builtin_amdgcn_mfma_f32_16x16x32_bf16(a[mt][1], bfr[1], acc, 0, 0, 0);
            acc = __builtin_amdgcn_mfma_f32_16x16x32_bf16(a[mt][2], bfr[2], acc, 0, 0, 0);
            acc = __builtin_amdgcn_mfma_f32_16x16x32_bf16(a[mt][3], bfr[3], acc, 0, 0, 0);
#pragma unroll
            for (int rr = 0; rr < 4; rr++)
                rmax[mt][rr] = fmaxf(rmax[mt][rr], acc[rr]);
        }
    }

#pragma unroll
    for (int mt = 0; mt < 5; mt++)
#pragma unroll
        for (int rr = 0; rr < 4; rr++) {
            float v = rmax[mt][rr];
            v = fmaxf(v, __shfl_xor(v, 1));
            v = fmaxf(v, __shfl_xor(v, 2));
            v = fmaxf(v, __shfl_xor(v, 4));
            v = fmaxf(v, __shfl_xor(v, 8));
            rmax[mt][rr] = v;
        }
    float s0 = 0.f, s1 = 0.f;
#pragma unroll
    for (int mt = 0; mt < 5; mt++)
#pragma unroll
        for (int rr = 0; rr < 4; rr++) {
            int prow = mt * 16 + quad * 4 + rr;
            float v = rmax[mt][rr];
            if (prow < 35) s0 += v;
            else if (prow < 70) s1 += v;
        }
    s0 += __shfl_xor(s0, 16); s0 += __shfl_xor(s0, 32);
    s1 += __shfl_xor(s1, 16); s1 += __shfl_xor(s1, 32);
    if (lane == 0) {
        int qb0 = qp * 2, qb1 = qp * 2 + 1;
        out[(size_t)qb0 * (2 * B_) + side * B_ + pb] = s0;
        out[(size_t)qb1 * (2 * B_) + side * B_ + pb] = s1;
    }
}

// ---------------- launch ----------------
extern "C" void kernel_launch(void* const* d_in, const int* in_sizes, int n_in,
                              void* d_out, int out_size, void* d_ws, size_t ws_size,
                              hipStream_t stream) {
    const float* qh   = (const float*)d_in[0];
    const float* ph   = (const float*)d_in[1];
    const float* nh   = (const float*)d_in[2];
    const float* W    = (const float*)d_in[3];
    const float* bias = (const float*)d_in[4];
    const void* pmask = d_in[5];
    const void* nmask = d_in[6];
    float* out = (float*)d_out;
    char* ws = (char*)d_ws;

    constexpr size_t CTRL_OFF  = 0;                          // 256 B
    constexpr size_t WTHI_OFF  = 256;                        // 196608 B
    constexpr size_t MASKC_OFF = WTHI_OFF + 196608;          // 34560 B -> ends 231424
    constexpr size_t SSQ_OFF   = 231424;                     // 147456 B
    constexpr size_t X_OFF     = SSQ_OFF + 147456;           // 19415040 B
    constexpr size_t QFRAG_OFF = X_OFF + (size_t)NROWS * D_ * 4;   // 983040 B
    constexpr size_t PFRAG_OFF = QFRAG_OFF + 983040;         // 9437184 B

    unsigned int* ctrl     = (unsigned int*)(ws + CTRL_OFF);
    unsigned short* wthi   = (unsigned short*)(ws + WTHI_OFF);
    unsigned char* maskc   = (unsigned char*)(ws + MASKC_OFF);
    float* ssq             = (float*)(ws + SSQ_OFF);
    float* x               = (float*)(ws + X_OFF);
    unsigned short* qfrag  = (unsigned short*)(ws + QFRAG_OFF);
    unsigned short* pfrag  = (unsigned short*)(ws + PFRAG_OFF);

    prep_k<<<193, 256, 0, stream>>>(W, wthi, (const unsigned int*)pmask, ctrl, ssq);
    proj_k<<<593 + 135, 256, 0, stream>>>(qh, ph, nh, wthi, bias, x, ssq,
                                          pmask, nmask, ctrl, maskc);
    scatter_k<<<2544, 256, 0, stream>>>(x, ssq, maskc, qfrag, pfrag);
    interact_k<<<2304, 256, 0, stream>>>(qfrag, pfrag, out);
}

// Round 8
// 196.236 us; speedup vs baseline: 1.0236x; 1.0236x over previous
//
#include <hip/hip_runtime.h>

typedef __attribute__((ext_vector_type(4))) float f32x4;
typedef __attribute__((ext_vector_type(8))) short s16x8;
typedef __attribute__((ext_vector_type(4))) short s16x4;
typedef __bf16 bf16x4 __attribute__((ext_vector_type(4)));

#define B_   96
#define NQ   35
#define LP   180
#define H_   768
#define D_   128
#define NEGF (-1e30f)

#define NROWS 37920
#define QROWS 3360
#define PROWS 17280

__device__ __forceinline__ unsigned short f2bf(float f) {
    return __builtin_bit_cast(unsigned short, (__bf16)f);
}

__device__ __forceinline__ s16x8 pack_bf16(f32x4 v0, f32x4 v1) {
    bf16x4 h0 = __builtin_convertvector(v0, bf16x4);
    bf16x4 h1 = __builtin_convertvector(v1, bf16x4);
    s16x4 a = __builtin_bit_cast(s16x4, h0), b = __builtin_bit_cast(s16x4, h1);
    return __builtin_shufflevector(a, b, 0, 1, 2, 3, 4, 5, 6, 7);
}

// async global->LDS, 16 B per lane; lds dest must be wave-uniform (HW adds lane*16)
__device__ __forceinline__ void glds16(const void* g, void* l) {
    __builtin_amdgcn_global_load_lds(
        (const __attribute__((address_space(1))) unsigned int*)g,
        (__attribute__((address_space(3))) unsigned int*)l,
        16, 0, 0);
}

// ---------------- prep: wt_build (blocks 0-47) + mask canon w/ local detect (48-182) ----
// Mask canon moved here from proj (proj is now fused and needs maskc as an INPUT).
// Each canon block re-runs the dtype detection locally on pmask's first 17280 bytes
// (4320 words) -- no global ctrl cell, no cross-kernel ordering hazard. 135 x 17 KB of
// redundant L2 reads, negligible.
__global__ __launch_bounds__(256) void prep_k(
    const float* __restrict__ W, unsigned short* __restrict__ wthi,
    const void* __restrict__ pm, const void* __restrict__ nm,
    unsigned char* __restrict__ maskc) {
    __shared__ unsigned int rr[256];
    int b = blockIdx.x, t = threadIdx.x;
    if (b < 48) {
        int tid = b * 256 + t;
        int nt = tid / (24 * 64);
        int r = tid - nt * 24 * 64;
        int ks = r / 64, lane = r - ks * 64;
        int m = lane & 15, quad = lane >> 4;
        unsigned short* o = wthi + (size_t)tid * 8;
#pragma unroll
        for (int j = 0; j < 8; j++) {
            int k = ks * 32 + quad * 8 + j;
            o[j] = f2bf(W[(size_t)k * D_ + nt * 16 + m]);
        }
    } else {
        const unsigned int* pw = (const unsigned int*)pm;
        unsigned int f1 = 0, f3 = 0, f4 = 0;
        for (int w = t; w < 4320; w += 256) {
            unsigned int v = pw[w];
            f1 |= v & 0x0000ff00u;                 // byte %4==1 -> 1-byte layout
            f3 |= v & 0xff000000u;                 // byte %4==3 -> float32
            if (w & 1) f4 |= v & 0x000000ffu;      // byte %8==4 -> int32
        }
        rr[t] = f1; __syncthreads();
        for (int s2 = 128; s2; s2 >>= 1) { if (t < s2) rr[t] |= rr[t + s2]; __syncthreads(); }
        unsigned int c1 = rr[0]; __syncthreads();
        rr[t] = f3; __syncthreads();
        for (int s2 = 128; s2; s2 >>= 1) { if (t < s2) rr[t] |= rr[t + s2]; __syncthreads(); }
        unsigned int c3 = rr[0]; __syncthreads();
        rr[t] = f4; __syncthreads();
        for (int s2 = 128; s2; s2 >>= 1) { if (t < s2) rr[t] |= rr[t + s2]; __syncthreads(); }
        unsigned int c4 = rr[0];
        int i = (b - 48) * 256 + t;                // < 34560 exactly (135 blocks)
        const void* src = (i < B_ * LP) ? pm : nm;
        int j = (i < B_ * LP) ? i : i - B_ * LP;
        bool bit;
        if (c1 > 0)       bit = ((const unsigned char*)src)[j] != 0;
        else if (c3 > 0)  bit = ((const float*)src)[j] != 0.0f;
        else if (c4 > 0)  bit = ((const int*)src)[j] != 0;
        else              bit = ((const long long*)src)[j] != 0;
        maskc[i] = bit ? 1 : 0;
    }
}

// ---------------- proj v10: passage-fused proj+normalize+scatter ------------------------
// R7 verdict: proj's ~50 us floor survived FIVE structures (sync, pipeline depth,
// concurrency, occupancy, traffic all falsified) -- stop polishing it, DELETE work.
// Key: normalization is per (passage, d). One block = one passage (or 2 q-passages),
// 8 waves x 16 cols each => each wave's acc holds the full (passage x its-cols) slab:
//   - ssq = in-wave reduce (ZERO atomics, no prep zeroing)
//   - scale in-register, bf16 frags written via an LDS transpose
//   - mask-gather folded into the frag write
//   - the 19.4 MB f32 x write + re-read and ALL of scatter_k are deleted (2 fewer
//     dispatches' worth of work, one fewer launch)
// Grid: 192 passage-blocks (96 pos + 96 neg, 180 rows) + 48 q-blocks (70 rows).
// 512 threads, 96 KB LDS: double-buffered A staging (f32, glds, source-swizzled per
// rule #21), reused post-loop as the bf16 transpose buffer. Fragment layouts, MFMA
// order, swizzle identical to the proven v3-v9 lineage; ssq summation order changes
// (atomic tree -> in-wave tree), f32-exact-magnitude delta only.
__global__ __launch_bounds__(512, 1) void proj_k(
    const float* __restrict__ qh, const float* __restrict__ ph, const float* __restrict__ nh,
    const unsigned short* __restrict__ wthi, const float* __restrict__ bias,
    const unsigned char* __restrict__ maskc,
    unsigned short* __restrict__ qfrag, unsigned short* __restrict__ pfrag) {
    __shared__ float sb[24576];                      // 96 KB: 2 x 192 x 64 f32 staging
    int b = blockIdx.x, t = threadIdx.x;
    int wave = t >> 6, lane = t & 63;
    int m = lane & 15, quad = lane >> 4;
    unsigned short* xb = (unsigned short*)sb;        // post-loop transpose buffer

    if (b < 192) {
        // ================= passage block: 180 rows of pos (b<96) or neg =================
        const float* src = (b < 96) ? ph + (size_t)b * LP * H_
                                    : nh + (size_t)(b - 96) * LP * H_;
        // staging sources: wave covers local rows [wave*24, wave*24+24), 6 glds x 4 rows;
        // per-lane source chunk inverse-swizzled (cg = (lane&15) ^ 2*(row&7)); rows >= 180
        // clamp to 179 (staged dup, compute feeds garbage rows whose acc is discarded)
        const float* gp[6];
#pragma unroll
        for (int g = 0; g < 6; g++) {
            int rl = wave * 24 + g * 4 + (lane >> 4);
            int rc = rl < LP ? rl : LP - 1;
            gp[g] = src + (size_t)rc * H_ + (((lane & 15) ^ (2 * (rl & 7))) << 2);
        }

        f32x4 acc[12];
#pragma unroll
        for (int mt = 0; mt < 12; mt++) acc[mt] = (f32x4){0.f, 0.f, 0.f, 0.f};

        // prologue stage(0)
        {
            float* d0 = sb + wave * 1536;
#pragma unroll
            for (int g = 0; g < 6; g++) glds16(gp[g], d0 + g * 256);
        }
        __syncthreads();                             // drains vmcnt: buf0 ready

        for (int s = 0; s < 12; s++) {
            if (s < 11) {                            // stage(s+1) overlaps compute(s)
                float* d0 = sb + ((s + 1) & 1) * 12288 + wave * 1536;
#pragma unroll
                for (int g = 0; g < 6; g++) glds16(gp[g] + (s + 1) * 64, d0 + g * 256);
            }
            const float* bb = sb + (s & 1) * 12288;
#pragma unroll
            for (int ksg = 0; ksg < 2; ksg++) {
                s16x8 bf = *(const s16x8*)(wthi +
                           ((size_t)(wave * 24 + s * 2 + ksg) * 64 + lane) * 8);
                int kc = ksg * 8 + quad * 2;
#pragma unroll
                for (int mt = 0; mt < 12; mt++) {
                    int row = mt * 16 + m;
                    const float* fb = bb + row * 64 + ((kc ^ (2 * (row & 7))) << 2);
                    f32x4 lo = *(const f32x4*)fb, hi = *(const f32x4*)(fb + 4);
                    acc[mt] = __builtin_amdgcn_mfma_f32_16x16x32_bf16(
                        pack_bf16(lo, hi), bf, acc[mt], 0, 0, 0);
                }
            }
            __syncthreads();
        }

        // epilogue: bias + in-wave ssq + scale + LDS transpose + masked frag scatter
        float bv = bias[wave * 16 + m];
        float s2 = 0.f;
#pragma unroll
        for (int mt = 0; mt < 12; mt++)
#pragma unroll
            for (int r = 0; r < 4; r++) {
                int prow = mt * 16 + quad * 4 + r;
                float v = acc[mt][r] + bv;
                acc[mt][r] = v;
                if (prow < LP) s2 += v * v;
            }
        s2 += __shfl_xor(s2, 16); s2 += __shfl_xor(s2, 32);
        float sc = rsqrtf(fmaxf(s2, 1e-24f));
        __syncthreads();                             // staging dead; reuse as xb
#pragma unroll
        for (int mt = 0; mt < 12; mt++)
#pragma unroll
            for (int r = 0; r < 4; r++) {
                int prow = mt * 16 + quad * 4 + r;
                if (prow < LP) xb[prow * 136 + wave * 16 + m] = f2bf(acc[mt][r] * sc);
            }
        __syncthreads();
        const unsigned char* mk = maskc + b * LP;    // b>=96 lands in neg half: b*180 ok
        unsigned short* pdst = pfrag + (size_t)b * 24576;
#pragma unroll
        for (int i = 0; i < 6; i++) {                // 3072 chunks = 6 x 512
            int ch = t + i * 512;
            int ln = ch & 63;
            int l = ((ch >> 8) << 4) + (ln & 15);    // nt*16 + mm
            int lsrc = (l < LP && mk[l]) ? l : 0;
            int d0 = ((ch >> 6) & 3) * 32 + (ln >> 4) * 8;
            *(s16x8*)&pdst[(size_t)ch * 8] = *(const s16x8*)&xb[lsrc * 136 + d0];
        }
    } else {
        // ================= q block: 2 passages = 70 rows (5 mt tiles, pad 96) ===========
        int qp = b - 192;                            // [0,48)
        const float* src = qh + (size_t)qp * 70 * H_;
        const float* gp[3];
#pragma unroll
        for (int g = 0; g < 3; g++) {
            int rl = wave * 12 + g * 4 + (lane >> 4);
            int rc = rl < 70 ? rl : 69;
            gp[g] = src + (size_t)rc * H_ + (((lane & 15) ^ (2 * (rl & 7))) << 2);
        }

        f32x4 acc[5];
#pragma unroll
        for (int mt = 0; mt < 5; mt++) acc[mt] = (f32x4){0.f, 0.f, 0.f, 0.f};

        {
            float* d0 = sb + wave * 768;
#pragma unroll
            for (int g = 0; g < 3; g++) glds16(gp[g], d0 + g * 256);
        }
        __syncthreads();

        for (int s = 0; s < 12; s++) {
            if (s < 11) {
                float* d0 = sb + ((s + 1) & 1) * 6144 + wave * 768;
#pragma unroll
                for (int g = 0; g < 3; g++) glds16(gp[g] + (s + 1) * 64, d0 + g * 256);
            }
            const float* bb = sb + (s & 1) * 6144;
#pragma unroll
            for (int ksg = 0; ksg < 2; ksg++) {
                s16x8 bf = *(const s16x8*)(wthi +
                           ((size_t)(wave * 24 + s * 2 + ksg) * 64 + lane) * 8);
                int kc = ksg * 8 + quad * 2;
#pragma unroll
                for (int mt = 0; mt < 5; mt++) {
                    int row = mt * 16 + m;
                    const float* fb = bb + row * 64 + ((kc ^ (2 * (row & 7))) << 2);
                    f32x4 lo = *(const f32x4*)fb, hi = *(const f32x4*)(fb + 4);
                    acc[mt] = __builtin_amdgcn_mfma_f32_16x16x32_bf16(
                        pack_bf16(lo, hi), bf, acc[mt], 0, 0, 0);
                }
            }
            __syncthreads();
        }

        float bv = bias[wave * 16 + m];
        float s0 = 0.f, s1 = 0.f;
#pragma unroll
        for (int mt = 0; mt < 5; mt++)
#pragma unroll
            for (int r = 0; r < 4; r++) {
                int prow = mt * 16 + quad * 4 + r;
                float v = acc[mt][r] + bv;
                acc[mt][r] = v;
                if (prow < 35) s0 += v * v;
                else if (prow < 70) s1 += v * v;
            }
        s0 += __shfl_xor(s0, 16); s0 += __shfl_xor(s0, 32);
        s1 += __shfl_xor(s1, 16); s1 += __shfl_xor(s1, 32);
        float sc0 = rsqrtf(fmaxf(s0, 1e-24f));
        float sc1 = rsqrtf(fmaxf(s1, 1e-24f));
        __syncthreads();
#pragma unroll
        for (int mt = 0; mt < 5; mt++)
#pragma unroll
            for (int r = 0; r < 4; r++) {
                int prow = mt * 16 + quad * 4 + r;
                if (prow < 70)
                    xb[prow * 136 + wave * 16 + m] =
                        f2bf(acc[mt][r] * (prow < 35 ? sc0 : sc1));
            }
        __syncthreads();
        unsigned short* qdst = qfrag + (size_t)qp * 10240;
#pragma unroll
        for (int i = 0; i < 3; i++) {                // 1280 chunks = 2x512 + 256
            int ch = t + i * 512;
            if (ch < 1280) {
                int ln = ch & 63;
                int prow = ((ch >> 8) << 4) + (ln & 15);
                int d0 = ((ch >> 6) & 3) * 32 + (ln >> 4) * 8;
                s16x8 v = (s16x8){0, 0, 0, 0, 0, 0, 0, 0};
                if (prow < 70) v = *(const s16x8*)&xb[prow * 136 + d0];
                *(s16x8*)&qdst[(size_t)ch * 8] = v;
            }
        }
    }
}

// ---------------- late interaction: p-block staged via glds, XCD-pinned, mask-free ------
__global__ __launch_bounds__(256, 3) void interact_k(
    const unsigned short* __restrict__ qfrag, const unsigned short* __restrict__ pfrag,
    float* __restrict__ out) {
    __shared__ unsigned short plds[24576];           // 48 KB, shared by all 4 waves
    int wave = threadIdx.x >> 6, lane = threadIdx.x & 63;
    int b = blockIdx.x;                              // 2304 blocks
    int xcd = b & 7, i = b >> 3;                     // i in [0,288)
    int c = xcd * 24 + (i % 24);                     // [0,192)
    int qg = i / 24;                                 // [0,12)
    int side = c / 96, pb = c - side * 96;
    int qp = qg * 4 + wave;
    int m = lane & 15, quad = lane >> 4;

    const unsigned short* pbase = pfrag + (size_t)c * 24576;
    const unsigned short* qbase = qfrag + (size_t)qp * 10240;

#pragma unroll
    for (int ntl = 0; ntl < 3; ntl++) {
        int nt = wave * 3 + ntl;
#pragma unroll
        for (int ks = 0; ks < 4; ks++)
            glds16(pbase + ((size_t)(nt * 4 + ks) * 64 + lane) * 8,
                   &plds[(size_t)(nt * 4 + ks) * 512]);
    }

    s16x8 a[5][4];
#pragma unroll
    for (int mt = 0; mt < 5; mt++)
#pragma unroll
        for (int ks = 0; ks < 4; ks++)
            a[mt][ks] = *(const s16x8*)(qbase + ((size_t)(mt * 4 + ks) * 64 + lane) * 8);

    __syncthreads();                                 // drain staging

    const f32x4 zero4 = (f32x4){0.f, 0.f, 0.f, 0.f};
    float rmax[5][4];
#pragma unroll
    for (int mt = 0; mt < 5; mt++)
#pragma unroll
        for (int rr = 0; rr < 4; rr++) rmax[mt][rr] = NEGF;

    for (int nt = 0; nt < 12; nt++) {
        s16x8 bfr[4];
#pragma unroll
        for (int ks = 0; ks < 4; ks++)
            bfr[ks] = *(const s16x8*)&plds[((size_t)(nt * 4 + ks) * 64 + lane) * 8];
#pragma unroll
        for (int mt = 0; mt < 5; mt++) {
            f32x4 acc = __builtin_amdgcn_mfma_f32_16x16x32_bf16(a[mt][0], bfr[0], zero4, 0, 0, 0);
            acc = __builtin_amdgcn_mfma_f32_16x16x32_bf16(a[mt][1], bfr[1], acc, 0, 0, 0);
            acc = __builtin_amdgcn_mfma_f32_16x16x32_bf16(a[mt][2], bfr[2], acc, 0, 0, 0);
            acc = __builtin_amdgcn_mfma_f32_16x16x32_bf16(a[mt][3], bfr[3], acc, 0, 0, 0);
#pragma unroll
            for (int rr = 0; rr < 4; rr++)
                rmax[mt][rr] = fmaxf(rmax[mt][rr], acc[rr]);
        }
    }

#pragma unroll
    for (int mt = 0; mt < 5; mt++)
#pragma unroll
        for (int rr = 0; rr < 4; rr++) {
            float v = rmax[mt][rr];
            v = fmaxf(v, __shfl_xor(v, 1));
            v = fmaxf(v, __shfl_xor(v, 2));
            v = fmaxf(v, __shfl_xor(v, 4));
            v = fmaxf(v, __shfl_xor(v, 8));
            rmax[mt][rr] = v;
        }
    float s0 = 0.f, s1 = 0.f;
#pragma unroll
    for (int mt = 0; mt < 5; mt++)
#pragma unroll
        for (int rr = 0; rr < 4; rr++) {
            int prow = mt * 16 + quad * 4 + rr;
            float v = rmax[mt][rr];
            if (prow < 35) s0 += v;
            else if (prow < 70) s1 += v;
        }
    s0 += __shfl_xor(s0, 16); s0 += __shfl_xor(s0, 32);
    s1 += __shfl_xor(s1, 16); s1 += __shfl_xor(s1, 32);
    if (lane == 0) {
        int qb0 = qp * 2, qb1 = qp * 2 + 1;
        out[(size_t)qb0 * (2 * B_) + side * B_ + pb] = s0;
        out[(size_t)qb1 * (2 * B_) + side * B_ + pb] = s1;
    }
}

// ---------------- launch ----------------
extern "C" void kernel_launch(void* const* d_in, const int* in_sizes, int n_in,
                              void* d_out, int out_size, void* d_ws, size_t ws_size,
                              hipStream_t stream) {
    const float* qh   = (const float*)d_in[0];
    const float* ph   = (const float*)d_in[1];
    const float* nh   = (const float*)d_in[2];
    const float* W    = (const float*)d_in[3];
    const float* bias = (const float*)d_in[4];
    const void* pmask = d_in[5];
    const void* nmask = d_in[6];
    float* out = (float*)d_out;
    char* ws = (char*)d_ws;

    constexpr size_t WTHI_OFF  = 256;                        // 196608 B
    constexpr size_t MASKC_OFF = WTHI_OFF + 196608;          // 34560 B
    constexpr size_t QFRAG_OFF = MASKC_OFF + 34560;          // 983040 B
    constexpr size_t PFRAG_OFF = QFRAG_OFF + 983040;         // 9437184 B

    unsigned short* wthi   = (unsigned short*)(ws + WTHI_OFF);
    unsigned char* maskc   = (unsigned char*)(ws + MASKC_OFF);
    unsigned short* qfrag  = (unsigned short*)(ws + QFRAG_OFF);
    unsigned short* pfrag  = (unsigned short*)(ws + PFRAG_OFF);

    prep_k<<<183, 256, 0, stream>>>(W, wthi, pmask, nmask, maskc);
    proj_k<<<240, 512, 0, stream>>>(qh, ph, nh, wthi, bias, maskc, qfrag, pfrag);
    interact_k<<<2304, 256, 0, stream>>>(qfrag, pfrag, out);
}